// Round 10
// baseline (483.338 us; speedup 1.0000x reference)
//
#include <hip/hip_runtime.h>
#include <stdint.h>

#define B_ 4
#define T_ 8192
#define C_ 1024
#define BT_ (B_*T_)
#define NSEG 64
#define SLEN (T_/NSEG)
#define EPS_ 1e-5f
#define NT_ 16            // K-tiles: 1024/64

typedef __attribute__((ext_vector_type(8))) short short8;
typedef __attribute__((ext_vector_type(4))) float float4v;
typedef __attribute__((ext_vector_type(4))) unsigned short ushort4v;
typedef unsigned short u16;

__device__ __forceinline__ u16 f2bf(float f){
  union { float f; uint32_t u; } v; v.f = f;
  uint32_t r = v.u + 0x7FFFu + ((v.u >> 16) & 1u);   // round-to-nearest-even
  return (u16)(r >> 16);
}
__device__ __forceinline__ float bf2f(u16 h){
  union { uint32_t u; float f; } v; v.u = ((uint32_t)h) << 16;
  return v.f;
}
__device__ __forceinline__ void gload16(const void* g, void* l){
  __builtin_amdgcn_global_load_lds((__attribute__((address_space(1))) void*)(void*)g,
                                   (__attribute__((address_space(3))) void*)l,
                                   16, 0, 0);
}

// ---------------- weight casts fp32 -> bf16 (all 4 in one launch) ----------------
__global__ void castw4_kernel(const float* __restrict__ s0, const float* __restrict__ s1,
                              const float* __restrict__ s2, const float* __restrict__ s3,
                              u16* __restrict__ dst){
  const float* src = (blockIdx.y==0)?s0:((blockIdx.y==1)?s1:((blockIdx.y==2)?s2:s3));
  u16* out = dst + (size_t)blockIdx.y*1048576;
  int i = blockIdx.x*blockDim.x + threadIdx.x;
  float4v v = ((const float4v*)src)[i];
  ushort4v o;
  o.x=f2bf(v.x); o.y=f2bf(v.y); o.z=f2bf(v.z); o.w=f2bf(v.w);
  ((ushort4v*)out)[i] = o;
}

// ---------------- LayerNorm ----------------
__global__ __launch_bounds__(256) void ln_kernel(const float* __restrict__ x,
    const float* __restrict__ lw, const float* __restrict__ lb, u16* __restrict__ xxb)
{
  int row = blockIdx.x;
  int tid = threadIdx.x;
  float4v v = ((const float4v*)(x + (size_t)row*C_))[tid];
  float s1 = v.x+v.y+v.z+v.w;
  float s2 = v.x*v.x+v.y*v.y+v.z*v.z+v.w*v.w;
  #pragma unroll
  for (int off=32; off>0; off>>=1){
    s1 += __shfl_down(s1, off, 64);
    s2 += __shfl_down(s2, off, 64);
  }
  __shared__ float red1[4], red2[4];
  if ((tid&63)==0){ red1[tid>>6]=s1; red2[tid>>6]=s2; }
  __syncthreads();
  s1 = red1[0]+red1[1]+red1[2]+red1[3];
  s2 = red2[0]+red2[1]+red2[2]+red2[3];
  float mu = s1*(1.0f/C_);
  float rs = rsqrtf(s2*(1.0f/C_) - mu*mu + EPS_);
  float4v wv = ((const float4v*)lw)[tid];
  float4v bv = ((const float4v*)lb)[tid];
  ushort4v o;
  o.x = f2bf((v.x-mu)*rs*wv.x + bv.x);
  o.y = f2bf((v.y-mu)*rs*wv.y + bv.y);
  o.z = f2bf((v.z-mu)*rs*wv.z + bv.z);
  o.w = f2bf((v.w-mu)*rs*wv.w + bv.w);
  ((ushort4v*)(xxb + (size_t)row*C_))[tid] = o;
}

// ---------------- 2-barrier free-flow bf16 GEMM (round-8 verified) ----------------
// C = A(Mx1024)*B(Nx1024)^T; 256x256 tile, BK=64, 2 LDS buffers (128KB).
// ONE seal barrier + ONE open barrier per K-tile; all 24 ds_read_b128 and
// 64 MFMA free-flow between them (per-wave lgkmcnt data-deps, compiler-
// scheduled). Cross-wave hazards covered:
//  - stage-write into buf after seal BAR (every wave's MFMAs data-depend on
//    all its reads of buf -> reads complete before wave reaches the barrier)
//  - staged data visible: per-wave counted vmcnt(8) + open BAR
// Counted vmcnt: 8 loads (next tile) stay in flight across the gate;
// vmcnt(0) only at the last prefetched tile. No setprio (m190), no
// sched_barrier pinning (m141). Granule-XOR LDS swizzle (0 conflicts).
#define BAR() __builtin_amdgcn_s_barrier()

#define RD_A(DST, MH, BO) \
  _Pragma("unroll") for (int mt=0; mt<4; ++mt) \
    _Pragma("unroll") for (int ks=0; ks<2; ++ks) \
      DST[mt*2+ks] = *(const short8*)(lds + (BO) + ks*16384 + aoff0 + ((MH)*4+mt)*1024);

#define RD_B(DST, NH, BO) \
  _Pragma("unroll") for (int nt=0; nt<2; ++nt) \
    _Pragma("unroll") for (int ks=0; ks<2; ++ks) \
      DST[nt*2+ks] = *(const short8*)(lds + (BO) + ks*16384 + boff0 + ((NH)*2+nt)*1024);

#define MFMA_Q(AS, BS, MH, NH) \
  _Pragma("unroll") for (int ks=0; ks<2; ++ks) \
    _Pragma("unroll") for (int mt=0; mt<4; ++mt) \
      _Pragma("unroll") for (int nt=0; nt<2; ++nt) \
        acc[(MH)*4+mt][(NH)*2+nt] = __builtin_amdgcn_mfma_f32_16x16x32_bf16( \
            AS[mt*2+ks], BS[nt*2+ks], acc[(MH)*4+mt][(NH)*2+nt], 0,0,0);

template<bool F32OUT>
__global__ __launch_bounds__(512, 2) void gemm_dp(const u16* __restrict__ A,
    const u16* __restrict__ Bw, void* __restrict__ C0, void* __restrict__ C1,
    void* __restrict__ C2, int nbn)
{
  __shared__ __align__(1024) char lds[131072];   // A: [0,64K), B: [64K,128K)

  const int tid  = threadIdx.x;
  const int lane = tid & 63;
  const int wid  = tid >> 6;          // 0..7
  const int wr   = wid >> 2;          // 0..1  (M)
  const int wc   = wid & 3;           // 0..3  (N)

  // XCD mapping: xcd = lin%8 owns 16 consecutive bm; bn fastest inside.
  const int lin = blockIdx.x;
  const int x   = lin & 7;
  const int wl  = lin >> 3;
  const int bm  = x*16 + wl / nbn;
  const int bn  = wl % nbn;

  // ---- read-side addressing (frag reads) ----
  const int l15   = lane & 15;
  const int lswz  = ((lane>>4) ^ ((l15>>1)&3)) << 4;     // conflict-free XOR swizzle
  const int aoff0 = (wr*128 + l15)*64 + lswz;            // A region base 0
  const int boff0 = 65536 + (wc*64 + l15)*64 + lswz;     // B region base 64K

  // ---- staging addressing ----
  const int kk   = wid >> 2;          // kstep plane this wave stages
  const int rg0  = (wid & 3)*2;       // row-group pair
  const int kkL  = kk*16384;
  const char* Asrc = ((const char*)A)  + ((size_t)bm*256 + (lane>>2))*2048
                     + (((lane&3) ^ ((lane>>3)&3)) << 4) + kk*64;
  const char* Bsrc = ((const char*)Bw) + ((size_t)bn*256 + (lane>>2))*2048
                     + (((lane&3) ^ ((lane>>3)&3)) << 4) + kk*64;

  float4v acc[8][4];
  float4v zero = {0.f,0.f,0.f,0.f};
  #pragma unroll
  for (int i=0;i<8;++i)
    #pragma unroll
    for (int j=0;j<4;++j) acc[i][j]=zero;

  auto stage = [&](int bo, int ktB){
    #pragma unroll
    for (int h=0; h<2; ++h)
      #pragma unroll
      for (int q=0; q<2; ++q){
        const int rowoff = h*128 + (rg0+q)*16;
        gload16(Asrc + (size_t)rowoff*2048 + ktB, lds + bo + kkL + rowoff*64);
        gload16(Bsrc + (size_t)rowoff*2048 + ktB, lds + 65536 + bo + kkL + rowoff*64);
      }
  };

  // prologue: kt0 -> buf0, kt1 -> buf1; wait buf0 (8 of buf1 stay in flight)
  stage(0, 0);
  stage(32768, 128);
  asm volatile("s_waitcnt vmcnt(8)" ::: "memory");
  BAR();

  short8 A0r[8], A1r[8], B0r[4], B1r[4];

  // free-flow K-tile: quadrant order (0,0)->(0,1)->(1,1)->(1,0); reads placed
  // at first use, no inner barriers -- compiler hoists/interleaves with lgkm.
  #define TILE(KT, BO) do{ \
    RD_A(A0r, 0, BO); RD_B(B0r, 0, BO); \
    MFMA_Q(A0r, B0r, 0, 0); \
    RD_B(B1r, 1, BO); \
    MFMA_Q(A0r, B1r, 0, 1); \
    RD_A(A1r, 1, BO); \
    MFMA_Q(A1r, B1r, 1, 1); \
    MFMA_Q(A1r, B0r, 1, 0); \
    BAR();   /* seal: all waves' reads of BO retired (MFMA data-deps) */ \
    if ((KT) < NT_-2){ \
      stage(BO, ((KT)+2)*128); \
      asm volatile("s_waitcnt vmcnt(8)" ::: "memory"); \
      BAR();   /* open: next tile's buffer staged + visible */ \
    } else if ((KT) == NT_-2){ \
      asm volatile("s_waitcnt vmcnt(0)" ::: "memory"); \
      BAR(); \
    } \
  }while(0)

  for (int kt2=0; kt2<NT_; kt2+=2){
    TILE(kt2,   0);
    TILE(kt2+1, 32768);
  }
  #undef TILE

  // epilogue: D col = lane&15, row = (lane>>4)*4 + j
  const int cl = l15, rq = lane >> 4;
  const size_t rbase = (size_t)bm*256 + wr*128;
  const int sel = bn >> 2;
  const int c0 = (bn&3)*256 + wc*64;
  void* cb = (sel==0) ? C0 : ((sel==1) ? C1 : C2);
  #pragma unroll
  for (int mi=0;mi<8;++mi)
    #pragma unroll
    for (int ni=0;ni<4;++ni)
      #pragma unroll
      for (int j=0;j<4;++j){
        size_t rr = rbase + mi*16 + rq*4 + j;
        int    cc = c0 + ni*16 + cl;
        if constexpr (F32OUT) ((float*)cb)[rr*1024 + cc] = acc[mi][ni][j];
        else                  ((u16*)cb)[rr*1024 + cc]   = f2bf(acc[mi][ni][j]);
      }
}

// ---------------- WKV segmented scan (2-channel vectorized) ----------------
__global__ __launch_bounds__(256) void wkv_pass1(const u16* __restrict__ kb,
    const u16* __restrict__ vb, const float* __restrict__ tdecay,
    float* __restrict__ segsum)
{
  int c0  = (blockIdx.x*256 + threadIdx.x)*2;
  int seg = blockIdx.y, b = blockIdx.z;
  float td0 = -expf(tdecay[c0]),   td1 = -expf(tdecay[c0+1]);
  float d0  = expf(td0),           d1  = expf(td1);
  int t0    = seg*SLEN;
  float w0  = expf(td0*(float)t0), w1 = expf(td1*(float)t0);
  size_t base = ((size_t)b*T_ + t0)*C_ + c0;
  float s0 = 0.f, s1 = 0.f;
  #pragma unroll 2
  for (int i=0;i<SLEN;++i){
    uint32_t kk2 = *(const uint32_t*)(kb + base + (size_t)i*C_);
    uint32_t vv2 = *(const uint32_t*)(vb + base + (size_t)i*C_);
    float k0 = bf2f((u16)(kk2&0xffff)), k1 = bf2f((u16)(kk2>>16));
    float v0 = bf2f((u16)(vv2&0xffff)), v1 = bf2f((u16)(vv2>>16));
    s0 += k0*v0*w0; s1 += k1*v1*w1;
    w0 *= d0; w1 *= d1;
  }
  size_t o = ((size_t)b*NSEG + seg)*C_ + c0;
  segsum[o] = s0; segsum[o+1] = s1;
}

__global__ void wkv_pass2(const float* __restrict__ segsum, float* __restrict__ segoff){
  int idx = blockIdx.x*256 + threadIdx.x;   // over B_*C_
  int b = idx / C_, c = idx % C_;
  float run = 0.f;
  for (int s=0;s<NSEG;++s){
    size_t o = ((size_t)b*NSEG + s)*C_ + c;
    segoff[o] = run;
    run += segsum[o];
  }
}

__global__ __launch_bounds__(256) void wkv_pass3(const u16* __restrict__ kb,
    const u16* __restrict__ vb, const u16* __restrict__ rb,
    const float* __restrict__ tdecay, const float* __restrict__ tfirst,
    const float* __restrict__ segoff, u16* __restrict__ outb)
{
  int c0  = (blockIdx.x*256 + threadIdx.x)*2;
  int seg = blockIdx.y, b = blockIdx.z;
  float td0 = -expf(tdecay[c0]),   td1 = -expf(tdecay[c0+1]);
  float d0  = expf(td0),           d1  = expf(td1);
  float tf0 = expf(tfirst[c0]),    tf1 = expf(tfirst[c0+1]);
  int t0    = seg*SLEN;
  float w0  = expf(td0*(float)t0), w1 = expf(td1*(float)t0);
  size_t ho = ((size_t)b*NSEG + seg)*C_ + c0;
  float h0 = segoff[ho], h1 = segoff[ho+1];
  size_t base = ((size_t)b*T_ + t0)*C_ + c0;
  #pragma unroll 2
  for (int i=0;i<SLEN;++i){
    uint32_t kk2 = *(const uint32_t*)(kb + base + (size_t)i*C_);
    uint32_t vv2 = *(const uint32_t*)(vb + base + (size_t)i*C_);
    uint32_t rr2 = *(const uint32_t*)(rb + base + (size_t)i*C_);
    float k0 = bf2f((u16)(kk2&0xffff)), k1 = bf2f((u16)(kk2>>16));
    float v0 = bf2f((u16)(vv2&0xffff)), v1 = bf2f((u16)(vv2>>16));
    float r0 = bf2f((u16)(rr2&0xffff)), r1 = bf2f((u16)(rr2>>16));
    float wkv0 = h0 + k0*tf0,           wkv1 = h1 + k1*tf1;
    float sg0  = 1.f/(1.f + expf(-r0)), sg1  = 1.f/(1.f + expf(-r1));
    uint32_t o2 = (uint32_t)f2bf(sg0*wkv0) | ((uint32_t)f2bf(sg1*wkv1) << 16);
    *(uint32_t*)(outb + base + (size_t)i*C_) = o2;
    h0 += k0*v0*w0; h1 += k1*v1*w1;
    w0 *= d0; w1 *= d1;
  }
}

// ---------------- launcher ----------------
extern "C" void kernel_launch(void* const* d_in, const int* in_sizes, int n_in,
                              void* d_out, int out_size, void* d_ws, size_t ws_size,
                              hipStream_t stream)
{
  (void)in_sizes; (void)n_in; (void)out_size; (void)ws_size;
  const float* x   = (const float*)d_in[0];
  const float* tdc = (const float*)d_in[1];
  const float* tfc = (const float*)d_in[2];
  const float* Wk  = (const float*)d_in[3];
  const float* Wv  = (const float*)d_in[4];
  const float* Wr  = (const float*)d_in[5];
  const float* Wo  = (const float*)d_in[6];
  const float* lw  = (const float*)d_in[7];
  const float* lb  = (const float*)d_in[8];
  float* out = (float*)d_out;

  char* ws = (char*)d_ws;
  u16* xxb = (u16*)(ws);                            // 67MB (also reused as outb)
  u16* rb  = (u16*)(ws + 67108864);                 // 67MB
  u16* Wkb = (u16*)(ws + 134217728);                // 2MB each; Wk|Wv|Wr|Wo contiguous
  float* segsum = (float*)(ws + 142606336);         // 1MB
  float* segoff = (float*)(ws + 143654912);         // 1MB
  u16* kb = (u16*)d_out;                            // k,v live in d_out halves
  u16* vb = kb + (size_t)BT_*C_;
  u16* outb = xxb;
  u16* Wob = Wkb + 3u*1048576u;

  castw4_kernel<<<dim3(1024,4),256,0,stream>>>(Wk, Wv, Wr, Wo, Wkb);

  ln_kernel<<<BT_,256,0,stream>>>(x, lw, lb, xxb);

  // fused k|v|r GEMM: N = 3072 (12 bn-tiles), grid 1536
  gemm_dp<false><<<1536,512,0,stream>>>(xxb, Wkb, kb, vb, rb, 12);

  dim3 sg(C_/512, NSEG, B_);
  wkv_pass1<<<sg,256,0,stream>>>(kb, vb, tdc, segsum);
  wkv_pass2<<<16,256,0,stream>>>(segsum, segoff);
  wkv_pass3<<<sg,256,0,stream>>>(kb, vb, rb, tdc, tfc, segoff, outb);

  // output GEMM: N = 1024 (4 bn-tiles), grid 512
  gemm_dp<true><<<512,512,0,stream>>>(outb, Wob, out, out, out, 4);
}

// Round 11
// 477.848 us; speedup vs baseline: 1.0115x; 1.0115x over previous
//
#include <hip/hip_runtime.h>
#include <stdint.h>

#define B_ 4
#define T_ 8192
#define C_ 1024
#define BT_ (B_*T_)
#define NSEG 64
#define SLEN (T_/NSEG)
#define EPS_ 1e-5f
#define NT_ 16            // K-tiles: 1024/64

typedef __attribute__((ext_vector_type(8))) short short8;
typedef __attribute__((ext_vector_type(4))) float float4v;
typedef __attribute__((ext_vector_type(4))) unsigned short ushort4v;
typedef unsigned short u16;

__device__ __forceinline__ u16 f2bf(float f){
  union { float f; uint32_t u; } v; v.f = f;
  uint32_t r = v.u + 0x7FFFu + ((v.u >> 16) & 1u);   // round-to-nearest-even
  return (u16)(r >> 16);
}
__device__ __forceinline__ float bf2f(u16 h){
  union { uint32_t u; float f; } v; v.u = ((uint32_t)h) << 16;
  return v.f;
}
__device__ __forceinline__ void gload16(const void* g, void* l){
  __builtin_amdgcn_global_load_lds((__attribute__((address_space(1))) void*)(void*)g,
                                   (__attribute__((address_space(3))) void*)l,
                                   16, 0, 0);
}

// ---------------- weight casts fp32 -> bf16 (all 4 in one launch) ----------------
__global__ void castw4_kernel(const float* __restrict__ s0, const float* __restrict__ s1,
                              const float* __restrict__ s2, const float* __restrict__ s3,
                              u16* __restrict__ dst){
  const float* src = (blockIdx.y==0)?s0:((blockIdx.y==1)?s1:((blockIdx.y==2)?s2:s3));
  u16* out = dst + (size_t)blockIdx.y*1048576;
  int i = blockIdx.x*blockDim.x + threadIdx.x;
  float4v v = ((const float4v*)src)[i];
  ushort4v o;
  o.x=f2bf(v.x); o.y=f2bf(v.y); o.z=f2bf(v.z); o.w=f2bf(v.w);
  ((ushort4v*)out)[i] = o;
}

// ---------------- LayerNorm: wave-per-row, no barriers, no LDS ----------------
__global__ __launch_bounds__(256) void ln_kernel(const float* __restrict__ x,
    const float* __restrict__ lw, const float* __restrict__ lb, u16* __restrict__ xxb)
{
  const int lane = threadIdx.x & 63;
  const size_t row = (size_t)blockIdx.x*4 + (threadIdx.x>>6);
  const float* xr = x + row*C_;
  float4v v[4];
  #pragma unroll
  for (int j=0;j<4;++j) v[j] = ((const float4v*)xr)[lane + 64*j];
  float s1 = 0.f, s2 = 0.f;
  #pragma unroll
  for (int j=0;j<4;++j){
    s1 += v[j].x+v[j].y+v[j].z+v[j].w;
    s2 += v[j].x*v[j].x+v[j].y*v[j].y+v[j].z*v[j].z+v[j].w*v[j].w;
  }
  #pragma unroll
  for (int off=32; off>0; off>>=1){
    s1 += __shfl_xor(s1, off, 64);
    s2 += __shfl_xor(s2, off, 64);
  }
  float mu = s1*(1.0f/C_);
  float rs = rsqrtf(s2*(1.0f/C_) - mu*mu + EPS_);
  #pragma unroll
  for (int j=0;j<4;++j){
    float4v wv = ((const float4v*)lw)[lane + 64*j];
    float4v bv = ((const float4v*)lb)[lane + 64*j];
    ushort4v o;
    o.x = f2bf((v[j].x-mu)*rs*wv.x + bv.x);
    o.y = f2bf((v[j].y-mu)*rs*wv.y + bv.y);
    o.z = f2bf((v[j].z-mu)*rs*wv.z + bv.z);
    o.w = f2bf((v[j].w-mu)*rs*wv.w + bv.w);
    ((ushort4v*)(xxb + row*C_))[lane + 64*j] = o;
  }
}

// ---------------- 2-barrier free-flow bf16 GEMM (round-8 verified + T5) --------
// C = A(Mx1024)*B(Nx1024)^T; 256x256 tile, BK=64, 2 LDS buffers (128KB).
// ONE seal barrier + ONE open barrier per K-tile; all 24 ds_read_b128 and
// 64 MFMA free-flow between them. setprio(1) around MFMA clusters (T5):
// free-flow lets waves skew -> role diversity exists for the CU scheduler.
// Counted vmcnt(8) gate; vmcnt(0) only at the last prefetched tile.
// Granule-XOR LDS swizzle (0 conflicts measured).
#define BAR() __builtin_amdgcn_s_barrier()

#define RD_A(DST, MH, BO) \
  _Pragma("unroll") for (int mt=0; mt<4; ++mt) \
    _Pragma("unroll") for (int ks=0; ks<2; ++ks) \
      DST[mt*2+ks] = *(const short8*)(lds + (BO) + ks*16384 + aoff0 + ((MH)*4+mt)*1024);

#define RD_B(DST, NH, BO) \
  _Pragma("unroll") for (int nt=0; nt<2; ++nt) \
    _Pragma("unroll") for (int ks=0; ks<2; ++ks) \
      DST[nt*2+ks] = *(const short8*)(lds + (BO) + ks*16384 + boff0 + ((NH)*2+nt)*1024);

#define MFMA_Q(AS, BS, MH, NH) do{ \
  __builtin_amdgcn_s_setprio(1); \
  _Pragma("unroll") for (int ks=0; ks<2; ++ks) \
    _Pragma("unroll") for (int mt=0; mt<4; ++mt) \
      _Pragma("unroll") for (int nt=0; nt<2; ++nt) \
        acc[(MH)*4+mt][(NH)*2+nt] = __builtin_amdgcn_mfma_f32_16x16x32_bf16( \
            AS[mt*2+ks], BS[nt*2+ks], acc[(MH)*4+mt][(NH)*2+nt], 0,0,0); \
  __builtin_amdgcn_s_setprio(0); \
}while(0)

template<bool F32OUT>
__global__ __launch_bounds__(512, 2) void gemm_dp(const u16* __restrict__ A,
    const u16* __restrict__ Bw, void* __restrict__ C0, void* __restrict__ C1,
    void* __restrict__ C2, int nbn)
{
  __shared__ __align__(1024) char lds[131072];   // A: [0,64K), B: [64K,128K)

  const int tid  = threadIdx.x;
  const int lane = tid & 63;
  const int wid  = tid >> 6;          // 0..7
  const int wr   = wid >> 2;          // 0..1  (M)
  const int wc   = wid & 3;           // 0..3  (N)

  // XCD mapping: xcd = lin%8 owns 16 consecutive bm; bn fastest inside.
  const int lin = blockIdx.x;
  const int x   = lin & 7;
  const int wl  = lin >> 3;
  const int bm  = x*16 + wl / nbn;
  const int bn  = wl % nbn;

  // ---- read-side addressing (frag reads) ----
  const int l15   = lane & 15;
  const int lswz  = ((lane>>4) ^ ((l15>>1)&3)) << 4;     // conflict-free XOR swizzle
  const int aoff0 = (wr*128 + l15)*64 + lswz;            // A region base 0
  const int boff0 = 65536 + (wc*64 + l15)*64 + lswz;     // B region base 64K

  // ---- staging addressing ----
  const int kk   = wid >> 2;          // kstep plane this wave stages
  const int rg0  = (wid & 3)*2;       // row-group pair
  const int kkL  = kk*16384;
  const char* Asrc = ((const char*)A)  + ((size_t)bm*256 + (lane>>2))*2048
                     + (((lane&3) ^ ((lane>>3)&3)) << 4) + kk*64;
  const char* Bsrc = ((const char*)Bw) + ((size_t)bn*256 + (lane>>2))*2048
                     + (((lane&3) ^ ((lane>>3)&3)) << 4) + kk*64;

  float4v acc[8][4];
  float4v zero = {0.f,0.f,0.f,0.f};
  #pragma unroll
  for (int i=0;i<8;++i)
    #pragma unroll
    for (int j=0;j<4;++j) acc[i][j]=zero;

  auto stage = [&](int bo, int ktB){
    #pragma unroll
    for (int h=0; h<2; ++h)
      #pragma unroll
      for (int q=0; q<2; ++q){
        const int rowoff = h*128 + (rg0+q)*16;
        gload16(Asrc + (size_t)rowoff*2048 + ktB, lds + bo + kkL + rowoff*64);
        gload16(Bsrc + (size_t)rowoff*2048 + ktB, lds + 65536 + bo + kkL + rowoff*64);
      }
  };

  // prologue: kt0 -> buf0, kt1 -> buf1; wait buf0 (8 of buf1 stay in flight)
  stage(0, 0);
  stage(32768, 128);
  asm volatile("s_waitcnt vmcnt(8)" ::: "memory");
  BAR();

  short8 A0r[8], A1r[8], B0r[4], B1r[4];

  // free-flow K-tile: quadrant order (0,0)->(0,1)->(1,1)->(1,0); reads placed
  // at first use, no inner barriers -- compiler hoists/interleaves with lgkm.
  #define TILE(KT, BO) do{ \
    RD_A(A0r, 0, BO); RD_B(B0r, 0, BO); \
    MFMA_Q(A0r, B0r, 0, 0); \
    RD_B(B1r, 1, BO); \
    MFMA_Q(A0r, B1r, 0, 1); \
    RD_A(A1r, 1, BO); \
    MFMA_Q(A1r, B1r, 1, 1); \
    MFMA_Q(A1r, B0r, 1, 0); \
    BAR();   /* seal: all waves' reads of BO retired (MFMA data-deps) */ \
    if ((KT) < NT_-2){ \
      stage(BO, ((KT)+2)*128); \
      asm volatile("s_waitcnt vmcnt(8)" ::: "memory"); \
      BAR();   /* open: next tile's buffer staged + visible */ \
    } else if ((KT) == NT_-2){ \
      asm volatile("s_waitcnt vmcnt(0)" ::: "memory"); \
      BAR(); \
    } \
  }while(0)

  for (int kt2=0; kt2<NT_; kt2+=2){
    TILE(kt2,   0);
    TILE(kt2+1, 32768);
  }
  #undef TILE

  // epilogue: D col = lane&15, row = (lane>>4)*4 + j
  const int cl = l15, rq = lane >> 4;
  const size_t rbase = (size_t)bm*256 + wr*128;
  const int sel = bn >> 2;
  const int c0 = (bn&3)*256 + wc*64;
  void* cb = (sel==0) ? C0 : ((sel==1) ? C1 : C2);
  #pragma unroll
  for (int mi=0;mi<8;++mi)
    #pragma unroll
    for (int ni=0;ni<4;++ni)
      #pragma unroll
      for (int j=0;j<4;++j){
        size_t rr = rbase + mi*16 + rq*4 + j;
        int    cc = c0 + ni*16 + cl;
        if constexpr (F32OUT) ((float*)cb)[rr*1024 + cc] = acc[mi][ni][j];
        else                  ((u16*)cb)[rr*1024 + cc]   = f2bf(acc[mi][ni][j]);
      }
}

// ---------------- WKV segmented scan (round-8 scalar, 4 waves/SIMD TLP) --------
__global__ __launch_bounds__(256) void wkv_pass1(const u16* __restrict__ kb,
    const u16* __restrict__ vb, const float* __restrict__ tdecay,
    float* __restrict__ segsum)
{
  int c   = blockIdx.x*256 + threadIdx.x;
  int seg = blockIdx.y, b = blockIdx.z;
  float td = -expf(tdecay[c]);
  float d  = expf(td);
  int t0   = seg*SLEN;
  float w  = expf(td * (float)t0);
  size_t base = ((size_t)b*T_ + t0)*C_ + c;
  float s = 0.f;
  for (int i=0;i<SLEN;++i){
    float kk = bf2f(kb[base + (size_t)i*C_]);
    float vv = bf2f(vb[base + (size_t)i*C_]);
    s += kk*vv*w;
    w *= d;
  }
  segsum[((size_t)b*NSEG + seg)*C_ + c] = s;
}

__global__ void wkv_pass2(const float* __restrict__ segsum, float* __restrict__ segoff){
  int idx = blockIdx.x*256 + threadIdx.x;   // over B_*C_
  int b = idx / C_, c = idx % C_;
  float run = 0.f;
  for (int s=0;s<NSEG;++s){
    size_t o = ((size_t)b*NSEG + s)*C_ + c;
    segoff[o] = run;
    run += segsum[o];
  }
}

__global__ __launch_bounds__(256) void wkv_pass3(const u16* __restrict__ kb,
    const u16* __restrict__ vb, const u16* __restrict__ rb,
    const float* __restrict__ tdecay, const float* __restrict__ tfirst,
    const float* __restrict__ segoff, u16* __restrict__ outb)
{
  int c   = blockIdx.x*256 + threadIdx.x;
  int seg = blockIdx.y, b = blockIdx.z;
  float td = -expf(tdecay[c]);
  float d  = expf(td);
  float tf = expf(tfirst[c]);
  int t0   = seg*SLEN;
  float w  = expf(td * (float)t0);
  float hist = segoff[((size_t)b*NSEG + seg)*C_ + c];
  size_t base = ((size_t)b*T_ + t0)*C_ + c;
  for (int i=0;i<SLEN;++i){
    float kk = bf2f(kb[base + (size_t)i*C_]);
    float vv = bf2f(vb[base + (size_t)i*C_]);
    float rr = bf2f(rb[base + (size_t)i*C_]);
    float wkv = hist + kk*tf;
    float sg  = 1.f/(1.f + expf(-rr));
    outb[base + (size_t)i*C_] = f2bf(sg*wkv);
    hist += kk*vv*w;
    w *= d;
  }
}

// ---------------- launcher ----------------
extern "C" void kernel_launch(void* const* d_in, const int* in_sizes, int n_in,
                              void* d_out, int out_size, void* d_ws, size_t ws_size,
                              hipStream_t stream)
{
  (void)in_sizes; (void)n_in; (void)out_size; (void)ws_size;
  const float* x   = (const float*)d_in[0];
  const float* tdc = (const float*)d_in[1];
  const float* tfc = (const float*)d_in[2];
  const float* Wk  = (const float*)d_in[3];
  const float* Wv  = (const float*)d_in[4];
  const float* Wr  = (const float*)d_in[5];
  const float* Wo  = (const float*)d_in[6];
  const float* lw  = (const float*)d_in[7];
  const float* lb  = (const float*)d_in[8];
  float* out = (float*)d_out;

  char* ws = (char*)d_ws;
  u16* xxb = (u16*)(ws);                            // 67MB (also reused as outb)
  u16* rb  = (u16*)(ws + 67108864);                 // 67MB
  u16* Wkb = (u16*)(ws + 134217728);                // 2MB each; Wk|Wv|Wr|Wo contiguous
  float* segsum = (float*)(ws + 142606336);         // 1MB
  float* segoff = (float*)(ws + 143654912);         // 1MB
  u16* kb = (u16*)d_out;                            // k,v live in d_out halves
  u16* vb = kb + (size_t)BT_*C_;
  u16* outb = xxb;
  u16* Wob = Wkb + 3u*1048576u;

  castw4_kernel<<<dim3(1024,4),256,0,stream>>>(Wk, Wv, Wr, Wo, Wkb);

  ln_kernel<<<BT_/4,256,0,stream>>>(x, lw, lb, xxb);

  // fused k|v|r GEMM: N = 3072 (12 bn-tiles), grid 1536
  gemm_dp<false><<<1536,512,0,stream>>>(xxb, Wkb, kb, vb, rb, 12);

  dim3 sg(C_/256, NSEG, B_);
  wkv_pass1<<<sg,256,0,stream>>>(kb, vb, tdc, segsum);
  wkv_pass2<<<16,256,0,stream>>>(segsum, segoff);
  wkv_pass3<<<sg,256,0,stream>>>(kb, vb, rb, tdc, tfc, segoff, outb);

  // output GEMM: N = 1024 (4 bn-tiles), grid 512
  gemm_dp<true><<<512,512,0,stream>>>(outb, Wob, out, out, out, 4);
}

// Round 12
// 455.207 us; speedup vs baseline: 1.0618x; 1.0497x over previous
//
#include <hip/hip_runtime.h>
#include <stdint.h>

#define B_ 4
#define T_ 8192
#define C_ 1024
#define BT_ (B_*T_)
#define NSEG 64
#define SLEN (T_/NSEG)
#define EPS_ 1e-5f
#define NT_ 16            // K-tiles: 1024/64

typedef __attribute__((ext_vector_type(8))) short short8;
typedef __attribute__((ext_vector_type(4))) float float4v;
typedef __attribute__((ext_vector_type(4))) unsigned short ushort4v;
typedef unsigned short u16;

__device__ __forceinline__ u16 f2bf(float f){
  union { float f; uint32_t u; } v; v.f = f;
  uint32_t r = v.u + 0x7FFFu + ((v.u >> 16) & 1u);   // round-to-nearest-even
  return (u16)(r >> 16);
}
__device__ __forceinline__ float bf2f(u16 h){
  union { uint32_t u; float f; } v; v.u = ((uint32_t)h) << 16;
  return v.f;
}
__device__ __forceinline__ void gload16(const void* g, void* l){
  __builtin_amdgcn_global_load_lds((__attribute__((address_space(1))) void*)(void*)g,
                                   (__attribute__((address_space(3))) void*)l,
                                   16, 0, 0);
}

// ---------------- weight casts fp32 -> bf16 (all 4 in one launch) ----------------
__global__ void castw4_kernel(const float* __restrict__ s0, const float* __restrict__ s1,
                              const float* __restrict__ s2, const float* __restrict__ s3,
                              u16* __restrict__ dst){
  const float* src = (blockIdx.y==0)?s0:((blockIdx.y==1)?s1:((blockIdx.y==2)?s2:s3));
  u16* out = dst + (size_t)blockIdx.y*1048576;
  int i = blockIdx.x*blockDim.x + threadIdx.x;
  float4v v = ((const float4v*)src)[i];
  ushort4v o;
  o.x=f2bf(v.x); o.y=f2bf(v.y); o.z=f2bf(v.z); o.w=f2bf(v.w);
  ((ushort4v*)out)[i] = o;
}

// ---------------- LayerNorm: wave-per-row, no barriers, no LDS ----------------
__global__ __launch_bounds__(256) void ln_kernel(const float* __restrict__ x,
    const float* __restrict__ lw, const float* __restrict__ lb, u16* __restrict__ xxb)
{
  const int lane = threadIdx.x & 63;
  const size_t row = (size_t)blockIdx.x*4 + (threadIdx.x>>6);
  const float* xr = x + row*C_;
  float4v v[4];
  #pragma unroll
  for (int j=0;j<4;++j) v[j] = ((const float4v*)xr)[lane + 64*j];
  float s1 = 0.f, s2 = 0.f;
  #pragma unroll
  for (int j=0;j<4;++j){
    s1 += v[j].x+v[j].y+v[j].z+v[j].w;
    s2 += v[j].x*v[j].x+v[j].y*v[j].y+v[j].z*v[j].z+v[j].w*v[j].w;
  }
  #pragma unroll
  for (int off=32; off>0; off>>=1){
    s1 += __shfl_xor(s1, off, 64);
    s2 += __shfl_xor(s2, off, 64);
  }
  float mu = s1*(1.0f/C_);
  float rs = rsqrtf(s2*(1.0f/C_) - mu*mu + EPS_);
  #pragma unroll
  for (int j=0;j<4;++j){
    float4v wv = ((const float4v*)lw)[lane + 64*j];
    float4v bv = ((const float4v*)lb)[lane + 64*j];
    ushort4v o;
    o.x = f2bf((v[j].x-mu)*rs*wv.x + bv.x);
    o.y = f2bf((v[j].y-mu)*rs*wv.y + bv.y);
    o.z = f2bf((v[j].z-mu)*rs*wv.z + bv.z);
    o.w = f2bf((v[j].w-mu)*rs*wv.w + bv.w);
    ((ushort4v*)(xxb + row*C_))[lane + 64*j] = o;
  }
}

// ---------------- 2-barrier free-flow bf16 GEMM (round-8 verified, no setprio) --
// C = A(Mx1024)*B(Nx1024)^T; 256x256 tile, BK=64, 2 LDS buffers (128KB).
// ONE seal barrier + ONE open barrier per K-tile; all 24 ds_read_b128 and
// 64 MFMA free-flow between them (per-wave lgkmcnt data-deps, compiler-
// scheduled). Cross-wave hazards covered:
//  - stage-write into buf after seal BAR (every wave's MFMAs data-depend on
//    all its reads of buf -> reads complete before wave reaches the barrier)
//  - staged data visible: per-wave counted vmcnt(8) + open BAR
// Counted vmcnt: 8 loads (next tile) stay in flight across the gate;
// vmcnt(0) only at the last prefetched tile. No setprio (hurt: r11 A/B
// 260->282 us, m190-consistent). Granule-XOR LDS swizzle (0 conflicts).
#define BAR() __builtin_amdgcn_s_barrier()

#define RD_A(DST, MH, BO) \
  _Pragma("unroll") for (int mt=0; mt<4; ++mt) \
    _Pragma("unroll") for (int ks=0; ks<2; ++ks) \
      DST[mt*2+ks] = *(const short8*)(lds + (BO) + ks*16384 + aoff0 + ((MH)*4+mt)*1024);

#define RD_B(DST, NH, BO) \
  _Pragma("unroll") for (int nt=0; nt<2; ++nt) \
    _Pragma("unroll") for (int ks=0; ks<2; ++ks) \
      DST[nt*2+ks] = *(const short8*)(lds + (BO) + ks*16384 + boff0 + ((NH)*2+nt)*1024);

#define MFMA_Q(AS, BS, MH, NH) \
  _Pragma("unroll") for (int ks=0; ks<2; ++ks) \
    _Pragma("unroll") for (int mt=0; mt<4; ++mt) \
      _Pragma("unroll") for (int nt=0; nt<2; ++nt) \
        acc[(MH)*4+mt][(NH)*2+nt] = __builtin_amdgcn_mfma_f32_16x16x32_bf16( \
            AS[mt*2+ks], BS[nt*2+ks], acc[(MH)*4+mt][(NH)*2+nt], 0,0,0);

template<bool F32OUT>
__global__ __launch_bounds__(512, 2) void gemm_dp(const u16* __restrict__ A,
    const u16* __restrict__ Bw, void* __restrict__ C0, void* __restrict__ C1,
    void* __restrict__ C2, int nbn)
{
  __shared__ __align__(1024) char lds[131072];   // A: [0,64K), B: [64K,128K)

  const int tid  = threadIdx.x;
  const int lane = tid & 63;
  const int wid  = tid >> 6;          // 0..7
  const int wr   = wid >> 2;          // 0..1  (M)
  const int wc   = wid & 3;           // 0..3  (N)

  // XCD mapping: xcd = lin%8 owns 16 consecutive bm; bn fastest inside.
  const int lin = blockIdx.x;
  const int x   = lin & 7;
  const int wl  = lin >> 3;
  const int bm  = x*16 + wl / nbn;
  const int bn  = wl % nbn;

  // ---- read-side addressing (frag reads) ----
  const int l15   = lane & 15;
  const int lswz  = ((lane>>4) ^ ((l15>>1)&3)) << 4;     // conflict-free XOR swizzle
  const int aoff0 = (wr*128 + l15)*64 + lswz;            // A region base 0
  const int boff0 = 65536 + (wc*64 + l15)*64 + lswz;     // B region base 64K

  // ---- staging addressing ----
  const int kk   = wid >> 2;          // kstep plane this wave stages
  const int rg0  = (wid & 3)*2;       // row-group pair
  const int kkL  = kk*16384;
  const char* Asrc = ((const char*)A)  + ((size_t)bm*256 + (lane>>2))*2048
                     + (((lane&3) ^ ((lane>>3)&3)) << 4) + kk*64;
  const char* Bsrc = ((const char*)Bw) + ((size_t)bn*256 + (lane>>2))*2048
                     + (((lane&3) ^ ((lane>>3)&3)) << 4) + kk*64;

  float4v acc[8][4];
  float4v zero = {0.f,0.f,0.f,0.f};
  #pragma unroll
  for (int i=0;i<8;++i)
    #pragma unroll
    for (int j=0;j<4;++j) acc[i][j]=zero;

  auto stage = [&](int bo, int ktB){
    #pragma unroll
    for (int h=0; h<2; ++h)
      #pragma unroll
      for (int q=0; q<2; ++q){
        const int rowoff = h*128 + (rg0+q)*16;
        gload16(Asrc + (size_t)rowoff*2048 + ktB, lds + bo + kkL + rowoff*64);
        gload16(Bsrc + (size_t)rowoff*2048 + ktB, lds + 65536 + bo + kkL + rowoff*64);
      }
  };

  // prologue: kt0 -> buf0, kt1 -> buf1; wait buf0 (8 of buf1 stay in flight)
  stage(0, 0);
  stage(32768, 128);
  asm volatile("s_waitcnt vmcnt(8)" ::: "memory");
  BAR();

  short8 A0r[8], A1r[8], B0r[4], B1r[4];

  // free-flow K-tile: quadrant order (0,0)->(0,1)->(1,1)->(1,0); reads placed
  // at first use, no inner barriers -- compiler hoists/interleaves with lgkm.
  #define TILE(KT, BO) do{ \
    RD_A(A0r, 0, BO); RD_B(B0r, 0, BO); \
    MFMA_Q(A0r, B0r, 0, 0); \
    RD_B(B1r, 1, BO); \
    MFMA_Q(A0r, B1r, 0, 1); \
    RD_A(A1r, 1, BO); \
    MFMA_Q(A1r, B1r, 1, 1); \
    MFMA_Q(A1r, B0r, 1, 0); \
    BAR();   /* seal: all waves' reads of BO retired (MFMA data-deps) */ \
    if ((KT) < NT_-2){ \
      stage(BO, ((KT)+2)*128); \
      asm volatile("s_waitcnt vmcnt(8)" ::: "memory"); \
      BAR();   /* open: next tile's buffer staged + visible */ \
    } else if ((KT) == NT_-2){ \
      asm volatile("s_waitcnt vmcnt(0)" ::: "memory"); \
      BAR(); \
    } \
  }while(0)

  for (int kt2=0; kt2<NT_; kt2+=2){
    TILE(kt2,   0);
    TILE(kt2+1, 32768);
  }
  #undef TILE

  // epilogue: D col = lane&15, row = (lane>>4)*4 + j
  const int cl = l15, rq = lane >> 4;
  const size_t rbase = (size_t)bm*256 + wr*128;
  const int sel = bn >> 2;
  const int c0 = (bn&3)*256 + wc*64;
  void* cb = (sel==0) ? C0 : ((sel==1) ? C1 : C2);
  #pragma unroll
  for (int mi=0;mi<8;++mi)
    #pragma unroll
    for (int ni=0;ni<4;++ni)
      #pragma unroll
      for (int j=0;j<4;++j){
        size_t rr = rbase + mi*16 + rq*4 + j;
        int    cc = c0 + ni*16 + cl;
        if constexpr (F32OUT) ((float*)cb)[rr*1024 + cc] = acc[mi][ni][j];
        else                  ((u16*)cb)[rr*1024 + cc]   = f2bf(acc[mi][ni][j]);
      }
}

// ---------------- WKV segmented scan (scalar, 4 waves/SIMD TLP) ----------------
__global__ __launch_bounds__(256) void wkv_pass1(const u16* __restrict__ kb,
    const u16* __restrict__ vb, const float* __restrict__ tdecay,
    float* __restrict__ segsum)
{
  int c   = blockIdx.x*256 + threadIdx.x;
  int seg = blockIdx.y, b = blockIdx.z;
  float td = -expf(tdecay[c]);
  float d  = expf(td);
  int t0   = seg*SLEN;
  float w  = expf(td * (float)t0);
  size_t base = ((size_t)b*T_ + t0)*C_ + c;
  float s = 0.f;
  for (int i=0;i<SLEN;++i){
    float kk = bf2f(kb[base + (size_t)i*C_]);
    float vv = bf2f(vb[base + (size_t)i*C_]);
    s += kk*vv*w;
    w *= d;
  }
  segsum[((size_t)b*NSEG + seg)*C_ + c] = s;
}

__global__ void wkv_pass2(const float* __restrict__ segsum, float* __restrict__ segoff){
  int idx = blockIdx.x*256 + threadIdx.x;   // over B_*C_
  int b = idx / C_, c = idx % C_;
  float run = 0.f;
  for (int s=0;s<NSEG;++s){
    size_t o = ((size_t)b*NSEG + s)*C_ + c;
    segoff[o] = run;
    run += segsum[o];
  }
}

__global__ __launch_bounds__(256) void wkv_pass3(const u16* __restrict__ kb,
    const u16* __restrict__ vb, const u16* __restrict__ rb,
    const float* __restrict__ tdecay, const float* __restrict__ tfirst,
    const float* __restrict__ segoff, u16* __restrict__ outb)
{
  int c   = blockIdx.x*256 + threadIdx.x;
  int seg = blockIdx.y, b = blockIdx.z;
  float td = -expf(tdecay[c]);
  float d  = expf(td);
  float tf = expf(tfirst[c]);
  int t0   = seg*SLEN;
  float w  = expf(td * (float)t0);
  float hist = segoff[((size_t)b*NSEG + seg)*C_ + c];
  size_t base = ((size_t)b*T_ + t0)*C_ + c;
  for (int i=0;i<SLEN;++i){
    float kk = bf2f(kb[base + (size_t)i*C_]);
    float vv = bf2f(vb[base + (size_t)i*C_]);
    float rr = bf2f(rb[base + (size_t)i*C_]);
    float wkv = hist + kk*tf;
    float sg  = 1.f/(1.f + expf(-rr));
    outb[base + (size_t)i*C_] = f2bf(sg*wkv);
    hist += kk*vv*w;
    w *= d;
  }
}

// ---------------- launcher ----------------
extern "C" void kernel_launch(void* const* d_in, const int* in_sizes, int n_in,
                              void* d_out, int out_size, void* d_ws, size_t ws_size,
                              hipStream_t stream)
{
  (void)in_sizes; (void)n_in; (void)out_size; (void)ws_size;
  const float* x   = (const float*)d_in[0];
  const float* tdc = (const float*)d_in[1];
  const float* tfc = (const float*)d_in[2];
  const float* Wk  = (const float*)d_in[3];
  const float* Wv  = (const float*)d_in[4];
  const float* Wr  = (const float*)d_in[5];
  const float* Wo  = (const float*)d_in[6];
  const float* lw  = (const float*)d_in[7];
  const float* lb  = (const float*)d_in[8];
  float* out = (float*)d_out;

  char* ws = (char*)d_ws;
  u16* xxb = (u16*)(ws);                            // 67MB (also reused as outb)
  u16* rb  = (u16*)(ws + 67108864);                 // 67MB
  u16* Wkb = (u16*)(ws + 134217728);                // 2MB each; Wk|Wv|Wr|Wo contiguous
  float* segsum = (float*)(ws + 142606336);         // 1MB
  float* segoff = (float*)(ws + 143654912);         // 1MB
  u16* kb = (u16*)d_out;                            // k,v live in d_out halves
  u16* vb = kb + (size_t)BT_*C_;
  u16* outb = xxb;
  u16* Wob = Wkb + 3u*1048576u;

  castw4_kernel<<<dim3(1024,4),256,0,stream>>>(Wk, Wv, Wr, Wo, Wkb);

  ln_kernel<<<BT_/4,256,0,stream>>>(x, lw, lb, xxb);

  // fused k|v|r GEMM: N = 3072 (12 bn-tiles), grid 1536
  gemm_dp<false><<<1536,512,0,stream>>>(xxb, Wkb, kb, vb, rb, 12);

  dim3 sg(C_/256, NSEG, B_);
  wkv_pass1<<<sg,256,0,stream>>>(kb, vb, tdc, segsum);
  wkv_pass2<<<16,256,0,stream>>>(segsum, segoff);
  wkv_pass3<<<sg,256,0,stream>>>(kb, vb, rb, tdc, tfc, segoff, outb);

  // output GEMM: N = 1024 (4 bn-tiles), grid 512
  gemm_dp<true><<<512,512,0,stream>>>(outb, Wob, out, out, out, 4);
}